// Round 7
// baseline (60.632 us; speedup 1.0000x reference)
//
#include <hip/hip_runtime.h>
#include <cstddef>

namespace {

constexpr int NB    = 8;
constexpr int LQn   = 2048;
constexpr int DM    = 256;
constexpr int S_TOT = 3840;   // 2048+1024+512+256

typedef __attribute__((ext_vector_type(8))) short  short8;
typedef __attribute__((ext_vector_type(4))) float  f32x4;
typedef __attribute__((ext_vector_type(8))) _Float16 half8;
typedef __attribute__((ext_vector_type(4))) _Float16 half4;
typedef __attribute__((ext_vector_type(2))) _Float16 half2v;

__device__ inline unsigned short f2bf(float f) {
  union { float f; unsigned u; } v; v.f = f;
  const unsigned u = v.u;
  return (unsigned short)((u + 0x7FFFu + ((u >> 16) & 1u)) >> 16);  // RNE
}

// ---------------------------------------------------------------------------
// Merged bf16-MFMA GEMM (value + proj in one launch), fused f32->bf16
// staging, f16 output.  1D grid of 736 blocks (R5 version, reverted from the
// R6 wblob/global_load_lds experiment which regressed +4.6 us):
//   id <  480: value GEMM  (240 row-blocks x 2 col-halves of W_val)
//   id >= 480: proj GEMM   (128 row-blocks x {W_off | W_attn})
// Col-tile partners are ADJACENT ids (id = c + 2*rowblk) -> A panel's second
// read is L3-served.
// Tile 128x128, BK=64, 4 waves (2x2), 4x4 frags of mfma_f32_16x16x32_bf16.
// LDS [128][64] bf16, T2 XOR swizzle (byte ^= (row&7)<<4) both sides.
// Pipeline: next k-tile's global loads issued before the MFMA phase; raw
// s_barrier + lgkmcnt(0) only (vmcnt stays outstanding across the barrier;
// the convert phase's data-dep wait absorbs the latency under MFMA).
// ---------------------------------------------------------------------------
__global__ __launch_bounds__(256) void gemm_bf16_k(
    const float* __restrict__ A_val, const float* __restrict__ A_prj,
    const float* __restrict__ W_val, const float* __restrict__ b_val,
    const float* __restrict__ W_off, const float* __restrict__ b_off,
    const float* __restrict__ W_att, const float* __restrict__ b_att,
    _Float16* __restrict__ out_val, _Float16* __restrict__ out_prj)
{
  __shared__ short As[128 * 64];
  __shared__ short Bs[128 * 64];

  const int tid  = threadIdx.x;
  const int lane = tid & 63;
  const int wid  = tid >> 6;
  const int wm   = wid >> 1;
  const int wn   = wid & 1;

  const int id = blockIdx.x;
  const float *A, *W, *bias;
  _Float16* out;
  int r0, c0;
  if (id < 480) {
    const int rb = id >> 1, c = id & 1;
    A = A_val; out = out_val; r0 = rb * 128; c0 = c * 128;
    W = W_val + (size_t)c0 * DM; bias = b_val + c0;
  } else {
    const int j = id - 480, rb = j >> 1, c = j & 1;
    A = A_prj; out = out_prj; r0 = rb * 128; c0 = c * 128;
    W = c ? W_att : W_off; bias = c ? b_att : b_off;
  }

  f32x4 acc[4][4] = {};

  float bv[4];
  #pragma unroll
  for (int ni = 0; ni < 4; ++ni)
    bv[ni] = bias[wn * 64 + ni * 16 + (lane & 15)];

  f32x4 pa0[4], pa1[4], pw0[4], pw1[4];

  auto load_tiles = [&](int k0) {
    #pragma unroll
    for (int i = 0; i < 4; ++i) {
      const int ch  = tid + i * 256;   // 0..1023
      const int row = ch >> 3;         // 0..127
      const int kg  = ch & 7;          // 0..7
      const size_t goff = (size_t)(r0 + row) * DM + k0 + kg * 8;
      pa0[i] = *reinterpret_cast<const f32x4*>(&A[goff]);
      pa1[i] = *reinterpret_cast<const f32x4*>(&A[goff + 4]);
      const size_t woff = (size_t)row * DM + k0 + kg * 8;
      pw0[i] = *reinterpret_cast<const f32x4*>(&W[woff]);
      pw1[i] = *reinterpret_cast<const f32x4*>(&W[woff + 4]);
    }
  };

  load_tiles(0);

  for (int k = 0; k < 4; ++k) {
    // phase 1: convert + LDS write (waits vmcnt via data dep)
    #pragma unroll
    for (int i = 0; i < 4; ++i) {
      const int ch  = tid + i * 256;
      const int row = ch >> 3;
      const int kg  = ch & 7;
      short8 sa, sw;
      #pragma unroll
      for (int j = 0; j < 4; ++j) {
        sa[j]     = (short)f2bf(pa0[i][j]);
        sa[j + 4] = (short)f2bf(pa1[i][j]);
        sw[j]     = (short)f2bf(pw0[i][j]);
        sw[j + 4] = (short)f2bf(pw1[i][j]);
      }
      const int byte = row * 128 + ((kg * 16) ^ ((row & 7) << 4));
      *reinterpret_cast<short8*>(reinterpret_cast<char*>(As) + byte) = sa;
      *reinterpret_cast<short8*>(reinterpret_cast<char*>(Bs) + byte) = sw;
    }
    if (k < 3) load_tiles((k + 1) * 64);

    asm volatile("s_waitcnt lgkmcnt(0)" ::: "memory");
    __builtin_amdgcn_sched_barrier(0);
    __builtin_amdgcn_s_barrier();
    __builtin_amdgcn_sched_barrier(0);

    // phase 2: fragments + MFMA
    #pragma unroll
    for (int ks = 0; ks < 2; ++ks) {
      const int kb = (ks * 32 + (lane >> 4) * 8) * 2;
      short8 af[4], bf[4];
      #pragma unroll
      for (int mi = 0; mi < 4; ++mi) {
        const int row = wm * 64 + mi * 16 + (lane & 15);
        const int byte = row * 128 + (kb ^ ((row & 7) << 4));
        af[mi] = *reinterpret_cast<const short8*>(
            reinterpret_cast<const char*>(As) + byte);
      }
      #pragma unroll
      for (int ni = 0; ni < 4; ++ni) {
        const int col = wn * 64 + ni * 16 + (lane & 15);
        const int byte = col * 128 + (kb ^ ((col & 7) << 4));
        bf[ni] = *reinterpret_cast<const short8*>(
            reinterpret_cast<const char*>(Bs) + byte);
      }
      #pragma unroll
      for (int mi = 0; mi < 4; ++mi)
        #pragma unroll
        for (int ni = 0; ni < 4; ++ni)
          acc[mi][ni] = __builtin_amdgcn_mfma_f32_16x16x32_bf16(
              af[mi], bf[ni], acc[mi][ni], 0, 0, 0);
    }

    asm volatile("s_waitcnt lgkmcnt(0)" ::: "memory");
    __builtin_amdgcn_sched_barrier(0);
    __builtin_amdgcn_s_barrier();
    __builtin_amdgcn_sched_barrier(0);
  }

  // epilogue: C/D layout col=lane&15, row=(lane>>4)*4+reg
  #pragma unroll
  for (int mi = 0; mi < 4; ++mi) {
    const int row = r0 + wm * 64 + mi * 16 + (lane >> 4) * 4;
    #pragma unroll
    for (int ni = 0; ni < 4; ++ni) {
      const int col = c0 + wn * 64 + ni * 16 + (lane & 15);
      #pragma unroll
      for (int j = 0; j < 4; ++j)
        out[(size_t)(row + j) * DM + col] = (_Float16)(acc[mi][ni][j] + bv[ni]);
    }
  }
}

// ---------------------------------------------------------------------------
// Sampler v4 (unchanged R5 version). Block = 512 threads = 8 queries,
// XCD-swizzled grid (n = blockIdx&7 -> batch slice L2-resident).
// Prep (t<256): (q,m,sub-level) -> 4-lane shfl softmax -> tap table in LDS.
// Gather: thread (q=wave, m, dg, th) does 8 taps; shfl_xor(4) partner merge.
// NOTE: launched TWICE this round (idempotent) -- measurement round: with
// R5 total G+S = 43.9 us known, total_R7 = G + 2S pins down S exactly.
// ---------------------------------------------------------------------------
__global__ __launch_bounds__(512) void sample_k(
    const _Float16* __restrict__ proj,    // (N*LQ, 256) f16
    const float* __restrict__ refp,       // (N, LQ, 4)
    const _Float16* __restrict__ value,   // (N, 3840, 256) f16, c = m*32+d
    float* __restrict__ out)              // (N, LQ, 256)
{
  __shared__ uint4 tap_s[8][136];   // [q][m*17 + tap], 17.4 KB

  const int d     = blockIdx.x;
  const int n     = d & 7;
  const int chunk = d >> 3;
  const int row0q = n * LQn + chunk * 8;
  const int t     = threadIdx.x;

  const int lens[4]   = {2048, 1024, 512, 256};
  const int starts[4] = {0, 2048, 3072, 3584};

  // ---- prep: softmax + tap table ----
  if (t < 256) {
    const int q   = t >> 5;
    const int m   = (t >> 2) & 7;
    const int sub = t & 3;              // == level l
    const int j0  = m * 16 + sub * 4;
    const size_t prow = (size_t)(row0q + q) * DM;

    const half4 offv = *reinterpret_cast<const half4*>(&proj[prow + j0]);
    const half4 lgv  = *reinterpret_cast<const half4*>(&proj[prow + 128 + j0]);
    float lg[4], off[4];
    #pragma unroll
    for (int i = 0; i < 4; ++i) { lg[i] = (float)lgv[i]; off[i] = (float)offv[i]; }

    float mx = fmaxf(fmaxf(lg[0], lg[1]), fmaxf(lg[2], lg[3]));
    mx = fmaxf(mx, __shfl_xor(mx, 1));
    mx = fmaxf(mx, __shfl_xor(mx, 2));
    float e[4], s = 0.f;
    #pragma unroll
    for (int i = 0; i < 4; ++i) { e[i] = __expf(lg[i] - mx); s += e[i]; }
    s += __shfl_xor(s, 1);
    s += __shfl_xor(s, 2);
    const float inv = 1.f / s;

    const int   T  = lens[sub];
    const int   st = starts[sub];
    const float fT = (float)T;
    const float rf = refp[(size_t)(row0q + q) * 4 + sub];
    #pragma unroll
    for (int i = 0; i < 4; ++i) {
      const float a  = e[i] * inv;
      const float ix = fmaf(rf, fT, off[i] - 0.5f);
      const float fl = floorf(ix);
      const float w1 = ix - fl;
      const int   i0 = (int)fl;
      const int   i1 = i0 + 1;
      const float wa = (i0 >= 0 && i0 < T) ? a * (1.f - w1) : 0.f;
      const float wb = (i1 >= 0 && i1 < T) ? a * w1 : 0.f;
      const int   r0b = (st + min(max(i0, 0), T - 1)) * 512;
      const int   r1b = (st + min(max(i1, 0), T - 1)) * 512;
      union { half2v h; unsigned u; } pw;
      pw.h.x = (_Float16)wa; pw.h.y = (_Float16)wb;
      uint4 ent; ent.x = pw.u; ent.y = (unsigned)r0b; ent.z = (unsigned)r1b; ent.w = 0u;
      tap_s[q][m * 17 + sub * 4 + i] = ent;
    }
  }
  __syncthreads();

  // ---- gather ----
  const int q  = t >> 6;          // wave id = query
  const int l  = t & 63;
  const int m  = l >> 3;
  const int dg = l & 3;
  const int th = (l >> 2) & 1;    // tap-half
  const char* vb = reinterpret_cast<const char*>(value) +
                   (size_t)n * S_TOT * 512 + m * 64 + dg * 16;

  float acc[8] = {};
  #pragma unroll
  for (int i = 0; i < 8; ++i) {
    const uint4 e = tap_s[q][m * 17 + th * 8 + i];
    union { unsigned u; half2v h; } pw; pw.u = e.x;
    const float wa = (float)pw.h.x;
    const float wb = (float)pw.h.y;
    const half8 v0 = *reinterpret_cast<const half8*>(vb + e.y);
    const half8 v1 = *reinterpret_cast<const half8*>(vb + e.z);
    #pragma unroll
    for (int j = 0; j < 8; ++j)
      acc[j] = fmaf(wa, (float)v0[j], fmaf(wb, (float)v1[j], acc[j]));
  }

  #pragma unroll
  for (int j = 0; j < 8; ++j) acc[j] += __shfl_xor(acc[j], 4);

  if (th == 0) {
    float* op = &out[(size_t)(row0q + q) * DM + m * 32 + dg * 8];
    f32x4 o0 = {acc[0], acc[1], acc[2], acc[3]};
    f32x4 o1 = {acc[4], acc[5], acc[6], acc[7]};
    *reinterpret_cast<f32x4*>(op)     = o0;
    *reinterpret_cast<f32x4*>(op + 4) = o1;
  }
}

}  // namespace

extern "C" void kernel_launch(void* const* d_in, const int* in_sizes, int n_in,
                              void* d_out, int out_size, void* d_ws, size_t ws_size,
                              hipStream_t stream) {
  const float* query  = (const float*)d_in[0];   // (8,2048,256)
  const float* refp   = (const float*)d_in[1];   // (8,2048,4,1)
  const float* inflat = (const float*)d_in[2];   // (8,3840,256)
  const float* W_val  = (const float*)d_in[5];   // (256,256)
  const float* b_val  = (const float*)d_in[6];   // (256,)
  const float* W_off  = (const float*)d_in[7];   // (128,256)
  const float* b_off  = (const float*)d_in[8];   // (128,)
  const float* W_attn = (const float*)d_in[9];   // (128,256)
  const float* b_attn = (const float*)d_in[10];  // (128,)
  float* out = (float*)d_out;

  // workspace: value f16 (30720*256 = 15.73 MB) | proj f16 (16384*256 = 8.4 MB)
  _Float16* value_h = (_Float16*)d_ws;
  _Float16* proj_h  = (_Float16*)((char*)d_ws +
                      (size_t)NB * S_TOT * DM * sizeof(_Float16));

  // merged GEMM: 480 value blocks + 256 proj blocks
  gemm_bf16_k<<<dim3(736), dim3(256), 0, stream>>>(
      inflat, query, W_val, b_val, W_off, b_off, W_attn, b_attn,
      value_h, proj_h);

  // softmax + bilinear sampling + head-mix (XCD-swizzled grid)
  // Launched twice (idempotent): measurement round to pin down the
  // GEMM/sampler time split. total = G + 2S; R5 gave G + S = 43.9 us.
  sample_k<<<dim3(NB * LQn / 8), dim3(512), 0, stream>>>(
      proj_h, refp, value_h, out);
  sample_k<<<dim3(NB * LQn / 8), dim3(512), 0, stream>>>(
      proj_h, refp, value_h, out);
}

// Round 8
// 42.995 us; speedup vs baseline: 1.4102x; 1.4102x over previous
//
#include <hip/hip_runtime.h>
#include <hip/hip_bf16.h>
#include <cstddef>

namespace {

constexpr int NB    = 8;
constexpr int LQn   = 2048;
constexpr int DM    = 256;
constexpr int S_TOT = 3840;   // 2048+1024+512+256

typedef __attribute__((ext_vector_type(8))) short  short8;
typedef __attribute__((ext_vector_type(4))) float  f32x4;
typedef __attribute__((ext_vector_type(8))) _Float16 half8;
typedef __attribute__((ext_vector_type(4))) _Float16 half4;
typedef __attribute__((ext_vector_type(2))) _Float16 half2v;

// pack 4+4 f32 -> 8 bf16 via native v_cvt_pk_bf16_f32 (m240: let the
// compiler emit it from __float22bfloat162_rn; hand-rolled RNE bit-twiddle
// was ~4-5 VALU insts/value and made the GEMM staging-VALU-bound)
union BF8 { __hip_bfloat162 h2[4]; short8 s8; };
__device__ inline short8 cvt8(const f32x4 a, const f32x4 b) {
  BF8 r;
  r.h2[0] = __float22bfloat162_rn(make_float2(a[0], a[1]));
  r.h2[1] = __float22bfloat162_rn(make_float2(a[2], a[3]));
  r.h2[2] = __float22bfloat162_rn(make_float2(b[0], b[1]));
  r.h2[3] = __float22bfloat162_rn(make_float2(b[2], b[3]));
  return r.s8;
}

// ---------------------------------------------------------------------------
// Merged bf16-MFMA GEMM (value + proj in one launch), f16 output.
// 1D grid of 736 blocks:
//   id <  480: value GEMM  (240 row-blocks x 2 col-halves of W_val)
//   id >= 480: proj GEMM   (128 row-blocks x {W_off | W_attn})
// Col-tile partners are ADJACENT ids -> A panel's second read is L3-served.
// Tile 128x128, BK=64, 4 waves (2x2), 4x4 frags of mfma_f32_16x16x32_bf16.
// LDS [128][64] bf16, T2 XOR swizzle (byte ^= (row&7)<<4) both sides.
// Pipeline: next k-tile's global loads issued before the MFMA phase; raw
// s_barrier + lgkmcnt(0) only (vmcnt stays outstanding across the barrier).
// NEW vs R5: (1) native v_cvt_pk_bf16_f32 staging converts; (2) LDS-staged
// epilogue -> 8x16B coalesced stores/thread instead of 64x2B scalar.
// ---------------------------------------------------------------------------
union SMem {
  struct { short A[128 * 64]; short B[128 * 64]; } ab;   // 32 KB k-loop
  _Float16 c[128 * 136];                                  // 34 KB epilogue
};

__global__ __launch_bounds__(256) void gemm_bf16_k(
    const float* __restrict__ A_val, const float* __restrict__ A_prj,
    const float* __restrict__ W_val, const float* __restrict__ b_val,
    const float* __restrict__ W_off, const float* __restrict__ b_off,
    const float* __restrict__ W_att, const float* __restrict__ b_att,
    _Float16* __restrict__ out_val, _Float16* __restrict__ out_prj)
{
  __shared__ SMem sm;
  short* As = sm.ab.A;
  short* Bs = sm.ab.B;

  const int tid  = threadIdx.x;
  const int lane = tid & 63;
  const int wid  = tid >> 6;
  const int wm   = wid >> 1;
  const int wn   = wid & 1;

  const int id = blockIdx.x;
  const float *A, *W, *bias;
  _Float16* out;
  int r0, c0;
  if (id < 480) {
    const int rb = id >> 1, c = id & 1;
    A = A_val; out = out_val; r0 = rb * 128; c0 = c * 128;
    W = W_val + (size_t)c0 * DM; bias = b_val + c0;
  } else {
    const int j = id - 480, rb = j >> 1, c = j & 1;
    A = A_prj; out = out_prj; r0 = rb * 128; c0 = c * 128;
    W = c ? W_att : W_off; bias = c ? b_att : b_off;
  }

  f32x4 acc[4][4] = {};

  float bv[4];
  #pragma unroll
  for (int ni = 0; ni < 4; ++ni)
    bv[ni] = bias[wn * 64 + ni * 16 + (lane & 15)];

  f32x4 pa0[4], pa1[4], pw0[4], pw1[4];

  auto load_tiles = [&](int k0) {
    #pragma unroll
    for (int i = 0; i < 4; ++i) {
      const int ch  = tid + i * 256;   // 0..1023
      const int row = ch >> 3;         // 0..127
      const int kg  = ch & 7;          // 0..7
      const size_t goff = (size_t)(r0 + row) * DM + k0 + kg * 8;
      pa0[i] = *reinterpret_cast<const f32x4*>(&A[goff]);
      pa1[i] = *reinterpret_cast<const f32x4*>(&A[goff + 4]);
      const size_t woff = (size_t)row * DM + k0 + kg * 8;
      pw0[i] = *reinterpret_cast<const f32x4*>(&W[woff]);
      pw1[i] = *reinterpret_cast<const f32x4*>(&W[woff + 4]);
    }
  };

  load_tiles(0);

  for (int k = 0; k < 4; ++k) {
    // phase 1: convert (v_cvt_pk_bf16_f32) + LDS write
    #pragma unroll
    for (int i = 0; i < 4; ++i) {
      const int ch  = tid + i * 256;
      const int row = ch >> 3;
      const int kg  = ch & 7;
      const short8 sa = cvt8(pa0[i], pa1[i]);
      const short8 sw = cvt8(pw0[i], pw1[i]);
      const int byte = row * 128 + ((kg * 16) ^ ((row & 7) << 4));
      *reinterpret_cast<short8*>(reinterpret_cast<char*>(As) + byte) = sa;
      *reinterpret_cast<short8*>(reinterpret_cast<char*>(Bs) + byte) = sw;
    }
    if (k < 3) load_tiles((k + 1) * 64);

    asm volatile("s_waitcnt lgkmcnt(0)" ::: "memory");
    __builtin_amdgcn_sched_barrier(0);
    __builtin_amdgcn_s_barrier();
    __builtin_amdgcn_sched_barrier(0);

    // phase 2: fragments + MFMA
    #pragma unroll
    for (int ks = 0; ks < 2; ++ks) {
      const int kb = (ks * 32 + (lane >> 4) * 8) * 2;
      short8 af[4], bf[4];
      #pragma unroll
      for (int mi = 0; mi < 4; ++mi) {
        const int row = wm * 64 + mi * 16 + (lane & 15);
        const int byte = row * 128 + (kb ^ ((row & 7) << 4));
        af[mi] = *reinterpret_cast<const short8*>(
            reinterpret_cast<const char*>(As) + byte);
      }
      #pragma unroll
      for (int ni = 0; ni < 4; ++ni) {
        const int col = wn * 64 + ni * 16 + (lane & 15);
        const int byte = col * 128 + (kb ^ ((col & 7) << 4));
        bf[ni] = *reinterpret_cast<const short8*>(
            reinterpret_cast<const char*>(Bs) + byte);
      }
      #pragma unroll
      for (int mi = 0; mi < 4; ++mi)
        #pragma unroll
        for (int ni = 0; ni < 4; ++ni)
          acc[mi][ni] = __builtin_amdgcn_mfma_f32_16x16x32_bf16(
              af[mi], bf[ni], acc[mi][ni], 0, 0, 0);
    }

    asm volatile("s_waitcnt lgkmcnt(0)" ::: "memory");
    __builtin_amdgcn_sched_barrier(0);
    __builtin_amdgcn_s_barrier();
    __builtin_amdgcn_sched_barrier(0);
  }

  // ---- epilogue: acc -> f16 LDS tile [128][136] -> coalesced 16B stores.
  // (last k-iteration's lgkmcnt(0)+barrier guarantees all frag reads done,
  // so As/Bs can be reused.)
  #pragma unroll
  for (int mi = 0; mi < 4; ++mi) {
    const int row = wm * 64 + mi * 16 + (lane >> 4) * 4;
    #pragma unroll
    for (int ni = 0; ni < 4; ++ni) {
      const int col = wn * 64 + ni * 16 + (lane & 15);
      #pragma unroll
      for (int j = 0; j < 4; ++j)
        sm.c[(row + j) * 136 + col] = (_Float16)(acc[mi][ni][j] + bv[ni]);
    }
  }
  __syncthreads();
  #pragma unroll
  for (int i = 0; i < 8; ++i) {
    const int ch  = tid + i * 256;   // 0..2047
    const int row = ch >> 4;         // 0..127
    const int cc  = ch & 15;         // 16B col-chunk
    const half8 v = *reinterpret_cast<const half8*>(&sm.c[row * 136 + cc * 8]);
    *reinterpret_cast<half8*>(&out[(size_t)(r0 + row) * DM + c0 + cc * 8]) = v;
  }
}

// ---------------------------------------------------------------------------
// Sampler v4 (unchanged, single launch). Block = 512 threads = 8 queries,
// XCD-swizzled grid (n = blockIdx&7 -> batch slice L2-resident).
// Prep (t<256): (q,m,sub-level) -> 4-lane shfl softmax -> tap table in LDS.
// Gather: thread (q=wave, m, dg, th) does 8 taps; shfl_xor(4) partner merge.
// Measured R7: S = 16.7 us (near the ~14-15 us L2-gather floor).
// ---------------------------------------------------------------------------
__global__ __launch_bounds__(512) void sample_k(
    const _Float16* __restrict__ proj,    // (N*LQ, 256) f16
    const float* __restrict__ refp,       // (N, LQ, 4)
    const _Float16* __restrict__ value,   // (N, 3840, 256) f16, c = m*32+d
    float* __restrict__ out)              // (N, LQ, 256)
{
  __shared__ uint4 tap_s[8][136];   // [q][m*17 + tap], 17.4 KB

  const int d     = blockIdx.x;
  const int n     = d & 7;
  const int chunk = d >> 3;
  const int row0q = n * LQn + chunk * 8;
  const int t     = threadIdx.x;

  const int lens[4]   = {2048, 1024, 512, 256};
  const int starts[4] = {0, 2048, 3072, 3584};

  // ---- prep: softmax + tap table ----
  if (t < 256) {
    const int q   = t >> 5;
    const int m   = (t >> 2) & 7;
    const int sub = t & 3;              // == level l
    const int j0  = m * 16 + sub * 4;
    const size_t prow = (size_t)(row0q + q) * DM;

    const half4 offv = *reinterpret_cast<const half4*>(&proj[prow + j0]);
    const half4 lgv  = *reinterpret_cast<const half4*>(&proj[prow + 128 + j0]);
    float lg[4], off[4];
    #pragma unroll
    for (int i = 0; i < 4; ++i) { lg[i] = (float)lgv[i]; off[i] = (float)offv[i]; }

    float mx = fmaxf(fmaxf(lg[0], lg[1]), fmaxf(lg[2], lg[3]));
    mx = fmaxf(mx, __shfl_xor(mx, 1));
    mx = fmaxf(mx, __shfl_xor(mx, 2));
    float e[4], s = 0.f;
    #pragma unroll
    for (int i = 0; i < 4; ++i) { e[i] = __expf(lg[i] - mx); s += e[i]; }
    s += __shfl_xor(s, 1);
    s += __shfl_xor(s, 2);
    const float inv = 1.f / s;

    const int   T  = lens[sub];
    const int   st = starts[sub];
    const float fT = (float)T;
    const float rf = refp[(size_t)(row0q + q) * 4 + sub];
    #pragma unroll
    for (int i = 0; i < 4; ++i) {
      const float a  = e[i] * inv;
      const float ix = fmaf(rf, fT, off[i] - 0.5f);
      const float fl = floorf(ix);
      const float w1 = ix - fl;
      const int   i0 = (int)fl;
      const int   i1 = i0 + 1;
      const float wa = (i0 >= 0 && i0 < T) ? a * (1.f - w1) : 0.f;
      const float wb = (i1 >= 0 && i1 < T) ? a * w1 : 0.f;
      const int   r0b = (st + min(max(i0, 0), T - 1)) * 512;
      const int   r1b = (st + min(max(i1, 0), T - 1)) * 512;
      union { half2v h; unsigned u; } pw;
      pw.h.x = (_Float16)wa; pw.h.y = (_Float16)wb;
      uint4 ent; ent.x = pw.u; ent.y = (unsigned)r0b; ent.z = (unsigned)r1b; ent.w = 0u;
      tap_s[q][m * 17 + sub * 4 + i] = ent;
    }
  }
  __syncthreads();

  // ---- gather ----
  const int q  = t >> 6;          // wave id = query
  const int l  = t & 63;
  const int m  = l >> 3;
  const int dg = l & 3;
  const int th = (l >> 2) & 1;    // tap-half
  const char* vb = reinterpret_cast<const char*>(value) +
                   (size_t)n * S_TOT * 512 + m * 64 + dg * 16;

  float acc[8] = {};
  #pragma unroll
  for (int i = 0; i < 8; ++i) {
    const uint4 e = tap_s[q][m * 17 + th * 8 + i];
    union { unsigned u; half2v h; } pw; pw.u = e.x;
    const float wa = (float)pw.h.x;
    const float wb = (float)pw.h.y;
    const half8 v0 = *reinterpret_cast<const half8*>(vb + e.y);
    const half8 v1 = *reinterpret_cast<const half8*>(vb + e.z);
    #pragma unroll
    for (int j = 0; j < 8; ++j)
      acc[j] = fmaf(wa, (float)v0[j], fmaf(wb, (float)v1[j], acc[j]));
  }

  #pragma unroll
  for (int j = 0; j < 8; ++j) acc[j] += __shfl_xor(acc[j], 4);

  if (th == 0) {
    float* op = &out[(size_t)(row0q + q) * DM + m * 32 + dg * 8];
    f32x4 o0 = {acc[0], acc[1], acc[2], acc[3]};
    f32x4 o1 = {acc[4], acc[5], acc[6], acc[7]};
    *reinterpret_cast<f32x4*>(op)     = o0;
    *reinterpret_cast<f32x4*>(op + 4) = o1;
  }
}

}  // namespace

extern "C" void kernel_launch(void* const* d_in, const int* in_sizes, int n_in,
                              void* d_out, int out_size, void* d_ws, size_t ws_size,
                              hipStream_t stream) {
  const float* query  = (const float*)d_in[0];   // (8,2048,256)
  const float* refp   = (const float*)d_in[1];   // (8,2048,4,1)
  const float* inflat = (const float*)d_in[2];   // (8,3840,256)
  const float* W_val  = (const float*)d_in[5];   // (256,256)
  const float* b_val  = (const float*)d_in[6];   // (256,)
  const float* W_off  = (const float*)d_in[7];   // (128,256)
  const float* b_off  = (const float*)d_in[8];   // (128,)
  const float* W_attn = (const float*)d_in[9];   // (128,256)
  const float* b_attn = (const float*)d_in[10];  // (128,)
  float* out = (float*)d_out;

  // workspace: value f16 (30720*256 = 15.73 MB) | proj f16 (16384*256 = 8.4 MB)
  _Float16* value_h = (_Float16*)d_ws;
  _Float16* proj_h  = (_Float16*)((char*)d_ws +
                      (size_t)NB * S_TOT * DM * sizeof(_Float16));

  // merged GEMM: 480 value blocks + 256 proj blocks
  gemm_bf16_k<<<dim3(736), dim3(256), 0, stream>>>(
      inflat, query, W_val, b_val, W_off, b_off, W_attn, b_attn,
      value_h, proj_h);

  // softmax + bilinear sampling + head-mix (XCD-swizzled grid)
  sample_k<<<dim3(NB * LQn / 8), dim3(512), 0, stream>>>(
      proj_h, refp, value_h, out);
}

// Round 9
// 41.855 us; speedup vs baseline: 1.4486x; 1.0272x over previous
//
#include <hip/hip_runtime.h>
#include <hip/hip_bf16.h>
#include <cstddef>

namespace {

constexpr int NB    = 8;
constexpr int LQn   = 2048;
constexpr int DM    = 256;
constexpr int S_TOT = 3840;   // 2048+1024+512+256

typedef __attribute__((ext_vector_type(8))) short  short8;
typedef __attribute__((ext_vector_type(4))) float  f32x4;
typedef __attribute__((ext_vector_type(8))) _Float16 half8;
typedef __attribute__((ext_vector_type(4))) _Float16 half4;
typedef __attribute__((ext_vector_type(2))) _Float16 half2v;

// pack 4+4 f32 -> 8 bf16 via native v_cvt_pk_bf16_f32
union BF8 { __hip_bfloat162 h2[4]; short8 s8; };
__device__ inline short8 cvt8(const f32x4 a, const f32x4 b) {
  BF8 r;
  r.h2[0] = __float22bfloat162_rn(make_float2(a[0], a[1]));
  r.h2[1] = __float22bfloat162_rn(make_float2(a[2], a[3]));
  r.h2[2] = __float22bfloat162_rn(make_float2(b[0], b[1]));
  r.h2[3] = __float22bfloat162_rn(make_float2(b[2], b[3]));
  return r.s8;
}

// ---------------------------------------------------------------------------
// Merged bf16-MFMA GEMM (value + proj in one launch), f16 output.
// 1D grid of 736 blocks, SAME-XCD col-partner remap:
//   rowblk = (id>>4)*8 + (id&7), c = (id>>3)&1  -> the two col-tiles of a
//   row panel are ids exactly 8 apart = same XCD (round-robin dispatch) =
//   A panel's second read is an L2 HIT (the old id-adjacent pairing put
//   partners on different XCDs; second read went to L3/HBM).
// Occupancy fix (R9): W is 131 KB, L2-resident -> its loads are ~250cyc L2
// hits, not the HBM stream. Drop W's 32-VGPR cross-k prefetch; stage W JIT
// (unroll 2) at the top of each staging phase. __launch_bounds__(256,3)
// targets VGPR<=170 -> 3 waves/SIMD (was ~190 -> 2).
// Tile 128x128, BK=64, 4 waves (2x2), 4x4 frags of mfma_f32_16x16x32_bf16.
// LDS [128][64] bf16, T2 XOR swizzle (byte ^= (row&7)<<4) both sides.
// Pipeline: A(k+1) loads issued before the barrier; raw s_barrier +
// lgkmcnt(0) only -> A's vmcnt stays outstanding across the MFMA phase.
// ---------------------------------------------------------------------------
union SMem {
  struct { short A[128 * 64]; short B[128 * 64]; } ab;   // 32 KB k-loop
  _Float16 c[128 * 136];                                  // 34 KB epilogue
};

__global__ __launch_bounds__(256, 3) void gemm_bf16_k(
    const float* __restrict__ A_val, const float* __restrict__ A_prj,
    const float* __restrict__ W_val, const float* __restrict__ b_val,
    const float* __restrict__ W_off, const float* __restrict__ b_off,
    const float* __restrict__ W_att, const float* __restrict__ b_att,
    _Float16* __restrict__ out_val, _Float16* __restrict__ out_prj)
{
  __shared__ SMem sm;
  short* As = sm.ab.A;
  short* Bs = sm.ab.B;

  const int tid  = threadIdx.x;
  const int lane = tid & 63;
  const int wid  = tid >> 6;
  const int wm   = wid >> 1;
  const int wn   = wid & 1;

  const int id = blockIdx.x;
  const float *A, *W, *bias;
  _Float16* out;
  int r0, c0;
  if (id < 480) {
    const int rb = (id >> 4) * 8 + (id & 7);   // 0..239
    const int c  = (id >> 3) & 1;
    A = A_val; out = out_val; r0 = rb * 128; c0 = c * 128;
    W = W_val + (size_t)c0 * DM; bias = b_val + c0;
  } else {
    const int j  = id - 480;
    const int rb = (j >> 4) * 8 + (j & 7);     // 0..127
    const int c  = (j >> 3) & 1;
    A = A_prj; out = out_prj; r0 = rb * 128; c0 = c * 128;
    W = c ? W_att : W_off; bias = c ? b_att : b_off;
  }

  f32x4 acc[4][4] = {};

  float bv[4];
  #pragma unroll
  for (int ni = 0; ni < 4; ++ni)
    bv[ni] = bias[wn * 64 + ni * 16 + (lane & 15)];

  f32x4 pa0[4], pa1[4];    // A prefetch only (W is JIT-staged)

  auto load_A = [&](int k0) {
    #pragma unroll
    for (int i = 0; i < 4; ++i) {
      const int ch  = tid + i * 256;   // 0..1023
      const int row = ch >> 3;         // 0..127
      const int kg  = ch & 7;          // 0..7
      const size_t goff = (size_t)(r0 + row) * DM + k0 + kg * 8;
      pa0[i] = *reinterpret_cast<const f32x4*>(&A[goff]);
      pa1[i] = *reinterpret_cast<const f32x4*>(&A[goff + 4]);
    }
  };

  load_A(0);

  for (int k = 0; k < 4; ++k) {
    const int k0 = k * 64;
    // phase 1a: W JIT staging (L2-hit loads; issued first so their latency
    // overlaps A's in-flight HBM tail; low register footprint)
    #pragma unroll 2
    for (int i = 0; i < 4; ++i) {
      const int ch  = tid + i * 256;
      const int row = ch >> 3;
      const int kg  = ch & 7;
      const size_t woff = (size_t)row * DM + k0 + kg * 8;
      const f32x4 w0 = *reinterpret_cast<const f32x4*>(&W[woff]);
      const f32x4 w1 = *reinterpret_cast<const f32x4*>(&W[woff + 4]);
      const short8 sw = cvt8(w0, w1);
      const int byte = row * 128 + ((kg * 16) ^ ((row & 7) << 4));
      *reinterpret_cast<short8*>(reinterpret_cast<char*>(Bs) + byte) = sw;
    }
    // phase 1b: A convert + LDS write (data-dep wait on pa_k)
    #pragma unroll
    for (int i = 0; i < 4; ++i) {
      const int ch  = tid + i * 256;
      const int row = ch >> 3;
      const int kg  = ch & 7;
      const short8 sa = cvt8(pa0[i], pa1[i]);
      const int byte = row * 128 + ((kg * 16) ^ ((row & 7) << 4));
      *reinterpret_cast<short8*>(reinterpret_cast<char*>(As) + byte) = sa;
    }
    // issue next A tile's HBM loads; stay in flight across barrier + MFMA
    if (k < 3) load_A(k0 + 64);

    asm volatile("s_waitcnt lgkmcnt(0)" ::: "memory");
    __builtin_amdgcn_sched_barrier(0);
    __builtin_amdgcn_s_barrier();
    __builtin_amdgcn_sched_barrier(0);

    // phase 2: fragments + MFMA
    #pragma unroll
    for (int ks = 0; ks < 2; ++ks) {
      const int kb = (ks * 32 + (lane >> 4) * 8) * 2;
      short8 af[4], bf[4];
      #pragma unroll
      for (int mi = 0; mi < 4; ++mi) {
        const int row = wm * 64 + mi * 16 + (lane & 15);
        const int byte = row * 128 + (kb ^ ((row & 7) << 4));
        af[mi] = *reinterpret_cast<const short8*>(
            reinterpret_cast<const char*>(As) + byte);
      }
      #pragma unroll
      for (int ni = 0; ni < 4; ++ni) {
        const int col = wn * 64 + ni * 16 + (lane & 15);
        const int byte = col * 128 + (kb ^ ((col & 7) << 4));
        bf[ni] = *reinterpret_cast<const short8*>(
            reinterpret_cast<const char*>(Bs) + byte);
      }
      #pragma unroll
      for (int mi = 0; mi < 4; ++mi)
        #pragma unroll
        for (int ni = 0; ni < 4; ++ni)
          acc[mi][ni] = __builtin_amdgcn_mfma_f32_16x16x32_bf16(
              af[mi], bf[ni], acc[mi][ni], 0, 0, 0);
    }

    asm volatile("s_waitcnt lgkmcnt(0)" ::: "memory");
    __builtin_amdgcn_sched_barrier(0);
    __builtin_amdgcn_s_barrier();
    __builtin_amdgcn_sched_barrier(0);
  }

  // epilogue: acc -> f16 LDS tile [128][136] -> coalesced 16B stores
  #pragma unroll
  for (int mi = 0; mi < 4; ++mi) {
    const int row = wm * 64 + mi * 16 + (lane >> 4) * 4;
    #pragma unroll
    for (int ni = 0; ni < 4; ++ni) {
      const int col = wn * 64 + ni * 16 + (lane & 15);
      #pragma unroll
      for (int j = 0; j < 4; ++j)
        sm.c[(row + j) * 136 + col] = (_Float16)(acc[mi][ni][j] + bv[ni]);
    }
  }
  __syncthreads();
  #pragma unroll
  for (int i = 0; i < 8; ++i) {
    const int ch  = tid + i * 256;   // 0..2047
    const int row = ch >> 4;         // 0..127
    const int cc  = ch & 15;         // 16B col-chunk
    const half8 v = *reinterpret_cast<const half8*>(&sm.c[row * 136 + cc * 8]);
    *reinterpret_cast<half8*>(&out[(size_t)(r0 + row) * DM + c0 + cc * 8]) = v;
  }
}

// ---------------------------------------------------------------------------
// Sampler v4 (unchanged). Block = 512 threads = 8 queries, XCD-swizzled
// grid (n = blockIdx&7 -> batch slice L2-resident).
// Prep (t<256): (q,m,sub-level) -> 4-lane shfl softmax -> tap table in LDS.
// Gather: thread (q=wave, m, dg, th) does 8 taps; shfl_xor(4) partner merge.
// Measured R7: S = 16.7 us (incl. launch overhead; ~10-11 us L2-gather floor).
// ---------------------------------------------------------------------------
__global__ __launch_bounds__(512) void sample_k(
    const _Float16* __restrict__ proj,    // (N*LQ, 256) f16
    const float* __restrict__ refp,       // (N, LQ, 4)
    const _Float16* __restrict__ value,   // (N, 3840, 256) f16, c = m*32+d
    float* __restrict__ out)              // (N, LQ, 256)
{
  __shared__ uint4 tap_s[8][136];   // [q][m*17 + tap], 17.4 KB

  const int d     = blockIdx.x;
  const int n     = d & 7;
  const int chunk = d >> 3;
  const int row0q = n * LQn + chunk * 8;
  const int t     = threadIdx.x;

  const int lens[4]   = {2048, 1024, 512, 256};
  const int starts[4] = {0, 2048, 3072, 3584};

  // ---- prep: softmax + tap table ----
  if (t < 256) {
    const int q   = t >> 5;
    const int m   = (t >> 2) & 7;
    const int sub = t & 3;              // == level l
    const int j0  = m * 16 + sub * 4;
    const size_t prow = (size_t)(row0q + q) * DM;

    const half4 offv = *reinterpret_cast<const half4*>(&proj[prow + j0]);
    const half4 lgv  = *reinterpret_cast<const half4*>(&proj[prow + 128 + j0]);
    float lg[4], off[4];
    #pragma unroll
    for (int i = 0; i < 4; ++i) { lg[i] = (float)lgv[i]; off[i] = (float)offv[i]; }

    float mx = fmaxf(fmaxf(lg[0], lg[1]), fmaxf(lg[2], lg[3]));
    mx = fmaxf(mx, __shfl_xor(mx, 1));
    mx = fmaxf(mx, __shfl_xor(mx, 2));
    float e[4], s = 0.f;
    #pragma unroll
    for (int i = 0; i < 4; ++i) { e[i] = __expf(lg[i] - mx); s += e[i]; }
    s += __shfl_xor(s, 1);
    s += __shfl_xor(s, 2);
    const float inv = 1.f / s;

    const int   T  = lens[sub];
    const int   st = starts[sub];
    const float fT = (float)T;
    const float rf = refp[(size_t)(row0q + q) * 4 + sub];
    #pragma unroll
    for (int i = 0; i < 4; ++i) {
      const float a  = e[i] * inv;
      const float ix = fmaf(rf, fT, off[i] - 0.5f);
      const float fl = floorf(ix);
      const float w1 = ix - fl;
      const int   i0 = (int)fl;
      const int   i1 = i0 + 1;
      const float wa = (i0 >= 0 && i0 < T) ? a * (1.f - w1) : 0.f;
      const float wb = (i1 >= 0 && i1 < T) ? a * w1 : 0.f;
      const int   r0b = (st + min(max(i0, 0), T - 1)) * 512;
      const int   r1b = (st + min(max(i1, 0), T - 1)) * 512;
      union { half2v h; unsigned u; } pw;
      pw.h.x = (_Float16)wa; pw.h.y = (_Float16)wb;
      uint4 ent; ent.x = pw.u; ent.y = (unsigned)r0b; ent.z = (unsigned)r1b; ent.w = 0u;
      tap_s[q][m * 17 + sub * 4 + i] = ent;
    }
  }
  __syncthreads();

  // ---- gather ----
  const int q  = t >> 6;          // wave id = query
  const int l  = t & 63;
  const int m  = l >> 3;
  const int dg = l & 3;
  const int th = (l >> 2) & 1;    // tap-half
  const char* vb = reinterpret_cast<const char*>(value) +
                   (size_t)n * S_TOT * 512 + m * 64 + dg * 16;

  float acc[8] = {};
  #pragma unroll
  for (int i = 0; i < 8; ++i) {
    const uint4 e = tap_s[q][m * 17 + th * 8 + i];
    union { unsigned u; half2v h; } pw; pw.u = e.x;
    const float wa = (float)pw.h.x;
    const float wb = (float)pw.h.y;
    const half8 v0 = *reinterpret_cast<const half8*>(vb + e.y);
    const half8 v1 = *reinterpret_cast<const half8*>(vb + e.z);
    #pragma unroll
    for (int j = 0; j < 8; ++j)
      acc[j] = fmaf(wa, (float)v0[j], fmaf(wb, (float)v1[j], acc[j]));
  }

  #pragma unroll
  for (int j = 0; j < 8; ++j) acc[j] += __shfl_xor(acc[j], 4);

  if (th == 0) {
    float* op = &out[(size_t)(row0q + q) * DM + m * 32 + dg * 8];
    f32x4 o0 = {acc[0], acc[1], acc[2], acc[3]};
    f32x4 o1 = {acc[4], acc[5], acc[6], acc[7]};
    *reinterpret_cast<f32x4*>(op)     = o0;
    *reinterpret_cast<f32x4*>(op + 4) = o1;
  }
}

}  // namespace

extern "C" void kernel_launch(void* const* d_in, const int* in_sizes, int n_in,
                              void* d_out, int out_size, void* d_ws, size_t ws_size,
                              hipStream_t stream) {
  const float* query  = (const float*)d_in[0];   // (8,2048,256)
  const float* refp   = (const float*)d_in[1];   // (8,2048,4,1)
  const float* inflat = (const float*)d_in[2];   // (8,3840,256)
  const float* W_val  = (const float*)d_in[5];   // (256,256)
  const float* b_val  = (const float*)d_in[6];   // (256,)
  const float* W_off  = (const float*)d_in[7];   // (128,256)
  const float* b_off  = (const float*)d_in[8];   // (128,)
  const float* W_attn = (const float*)d_in[9];   // (128,256)
  const float* b_attn = (const float*)d_in[10];  // (128,)
  float* out = (float*)d_out;

  // workspace: value f16 (30720*256 = 15.73 MB) | proj f16 (16384*256 = 8.4 MB)
  _Float16* value_h = (_Float16*)d_ws;
  _Float16* proj_h  = (_Float16*)((char*)d_ws +
                      (size_t)NB * S_TOT * DM * sizeof(_Float16));

  // merged GEMM: 480 value blocks + 256 proj blocks
  gemm_bf16_k<<<dim3(736), dim3(256), 0, stream>>>(
      inflat, query, W_val, b_val, W_off, b_off, W_attn, b_attn,
      value_h, proj_h);

  // softmax + bilinear sampling + head-mix (XCD-swizzled grid)
  sample_k<<<dim3(NB * LQn / 8), dim3(512), 0, stream>>>(
      proj_h, refp, value_h, out);
}

// Round 10
// 41.753 us; speedup vs baseline: 1.4521x; 1.0024x over previous
//
#include <hip/hip_runtime.h>
#include <hip/hip_bf16.h>
#include <cstddef>

namespace {

constexpr int NB    = 8;
constexpr int LQn   = 2048;
constexpr int DM    = 256;
constexpr int S_TOT = 3840;   // 2048+1024+512+256

typedef __attribute__((ext_vector_type(8))) short  short8;
typedef __attribute__((ext_vector_type(4))) float  f32x4;
typedef __attribute__((ext_vector_type(8))) _Float16 half8;
typedef __attribute__((ext_vector_type(4))) _Float16 half4;
typedef __attribute__((ext_vector_type(2))) _Float16 half2v;

// pack 4+4 f32 -> 8 bf16 via native v_cvt_pk_bf16_f32
union BF8 { __hip_bfloat162 h2[4]; short8 s8; };
__device__ inline short8 cvt8(const f32x4 a, const f32x4 b) {
  BF8 r;
  r.h2[0] = __float22bfloat162_rn(make_float2(a[0], a[1]));
  r.h2[1] = __float22bfloat162_rn(make_float2(a[2], a[3]));
  r.h2[2] = __float22bfloat162_rn(make_float2(b[0], b[1]));
  r.h2[3] = __float22bfloat162_rn(make_float2(b[2], b[3]));
  return r.s8;
}

// ---------------------------------------------------------------------------
// Merged bf16-MFMA GEMM (value + proj in one launch), f16 output.
// 1D grid of 736 blocks, XCD-ALIGNED mapping (R10): id = s*8 + batch, so
// every tile of batch n is computed by a block on XCD n (dispatch
// round-robins id%8 -> XCD). The sampler maps batch n -> XCD n too, so its
// value/proj reads hit the SAME XCD's still-warm L2 (3 MB/batch < 4 MB; L2
// is not flushed at kernel boundaries). Col partners (c=0/1) remain ids 8
// apart -> same XCD, concurrent -> A panel second read L2/L3-served.
//   id <  480: value tile  rb = (id&7)*30 + (id>>4), c = (id>>3)&1
//   id >= 480: proj  tile  rb = (j&7)*16  + (j>>4),  c = (j>>3)&1
// Tile 128x128, BK=64, 4 waves (2x2), 4x4 frags of mfma_f32_16x16x32_bf16.
// LDS [128][64] bf16, T2 XOR swizzle (byte ^= (row&7)<<4) both sides.
// W JIT-staged (L2-resident); A 1-k-step-ahead reg prefetch; raw s_barrier
// + lgkmcnt(0) only (A's vmcnt outstanding across the MFMA phase).
// ---------------------------------------------------------------------------
union SMem {
  struct { short A[128 * 64]; short B[128 * 64]; } ab;   // 32 KB k-loop
  _Float16 c[128 * 136];                                  // 34 KB epilogue
};

__global__ __launch_bounds__(256, 3) void gemm_bf16_k(
    const float* __restrict__ A_val, const float* __restrict__ A_prj,
    const float* __restrict__ W_val, const float* __restrict__ b_val,
    const float* __restrict__ W_off, const float* __restrict__ b_off,
    const float* __restrict__ W_att, const float* __restrict__ b_att,
    _Float16* __restrict__ out_val, _Float16* __restrict__ out_prj)
{
  __shared__ SMem sm;
  short* As = sm.ab.A;
  short* Bs = sm.ab.B;

  const int tid  = threadIdx.x;
  const int lane = tid & 63;
  const int wid  = tid >> 6;
  const int wm   = wid >> 1;
  const int wn   = wid & 1;

  const int id = blockIdx.x;
  const float *A, *W, *bias;
  _Float16* out;
  int r0, c0;
  if (id < 480) {
    const int x = id & 7;            // XCD == batch
    const int s = id >> 3;           // 0..59
    const int rb = x * 30 + (s >> 1);
    const int c  = s & 1;
    A = A_val; out = out_val; r0 = rb * 128; c0 = c * 128;
    W = W_val + (size_t)c0 * DM; bias = b_val + c0;
  } else {
    const int j = id - 480;
    const int x = j & 7;             // XCD == batch
    const int s = j >> 3;            // 0..31
    const int rb = x * 16 + (s >> 1);
    const int c  = s & 1;
    A = A_prj; out = out_prj; r0 = rb * 128; c0 = c * 128;
    W = c ? W_att : W_off; bias = c ? b_att : b_off;
  }

  f32x4 acc[4][4] = {};

  float bv[4];
  #pragma unroll
  for (int ni = 0; ni < 4; ++ni)
    bv[ni] = bias[wn * 64 + ni * 16 + (lane & 15)];

  f32x4 pa0[4], pa1[4];    // A prefetch only (W is JIT-staged)

  auto load_A = [&](int k0) {
    #pragma unroll
    for (int i = 0; i < 4; ++i) {
      const int ch  = tid + i * 256;   // 0..1023
      const int row = ch >> 3;         // 0..127
      const int kg  = ch & 7;          // 0..7
      const size_t goff = (size_t)(r0 + row) * DM + k0 + kg * 8;
      pa0[i] = *reinterpret_cast<const f32x4*>(&A[goff]);
      pa1[i] = *reinterpret_cast<const f32x4*>(&A[goff + 4]);
    }
  };

  load_A(0);

  for (int k = 0; k < 4; ++k) {
    const int k0 = k * 64;
    // phase 1a: W JIT staging (L2-hit loads, low register footprint)
    #pragma unroll 2
    for (int i = 0; i < 4; ++i) {
      const int ch  = tid + i * 256;
      const int row = ch >> 3;
      const int kg  = ch & 7;
      const size_t woff = (size_t)row * DM + k0 + kg * 8;
      const f32x4 w0 = *reinterpret_cast<const f32x4*>(&W[woff]);
      const f32x4 w1 = *reinterpret_cast<const f32x4*>(&W[woff + 4]);
      const short8 sw = cvt8(w0, w1);
      const int byte = row * 128 + ((kg * 16) ^ ((row & 7) << 4));
      *reinterpret_cast<short8*>(reinterpret_cast<char*>(Bs) + byte) = sw;
    }
    // phase 1b: A convert + LDS write (data-dep wait on pa_k)
    #pragma unroll
    for (int i = 0; i < 4; ++i) {
      const int ch  = tid + i * 256;
      const int row = ch >> 3;
      const int kg  = ch & 7;
      const short8 sa = cvt8(pa0[i], pa1[i]);
      const int byte = row * 128 + ((kg * 16) ^ ((row & 7) << 4));
      *reinterpret_cast<short8*>(reinterpret_cast<char*>(As) + byte) = sa;
    }
    // issue next A tile's HBM loads; stay in flight across barrier + MFMA
    if (k < 3) load_A(k0 + 64);

    asm volatile("s_waitcnt lgkmcnt(0)" ::: "memory");
    __builtin_amdgcn_sched_barrier(0);
    __builtin_amdgcn_s_barrier();
    __builtin_amdgcn_sched_barrier(0);

    // phase 2: fragments + MFMA
    #pragma unroll
    for (int ks = 0; ks < 2; ++ks) {
      const int kb = (ks * 32 + (lane >> 4) * 8) * 2;
      short8 af[4], bf[4];
      #pragma unroll
      for (int mi = 0; mi < 4; ++mi) {
        const int row = wm * 64 + mi * 16 + (lane & 15);
        const int byte = row * 128 + (kb ^ ((row & 7) << 4));
        af[mi] = *reinterpret_cast<const short8*>(
            reinterpret_cast<const char*>(As) + byte);
      }
      #pragma unroll
      for (int ni = 0; ni < 4; ++ni) {
        const int col = wn * 64 + ni * 16 + (lane & 15);
        const int byte = col * 128 + (kb ^ ((col & 7) << 4));
        bf[ni] = *reinterpret_cast<const short8*>(
            reinterpret_cast<const char*>(Bs) + byte);
      }
      #pragma unroll
      for (int mi = 0; mi < 4; ++mi)
        #pragma unroll
        for (int ni = 0; ni < 4; ++ni)
          acc[mi][ni] = __builtin_amdgcn_mfma_f32_16x16x32_bf16(
              af[mi], bf[ni], acc[mi][ni], 0, 0, 0);
    }

    asm volatile("s_waitcnt lgkmcnt(0)" ::: "memory");
    __builtin_amdgcn_sched_barrier(0);
    __builtin_amdgcn_s_barrier();
    __builtin_amdgcn_sched_barrier(0);
  }

  // epilogue: acc -> f16 LDS tile [128][136] -> coalesced 16B stores
  #pragma unroll
  for (int mi = 0; mi < 4; ++mi) {
    const int row = wm * 64 + mi * 16 + (lane >> 4) * 4;
    #pragma unroll
    for (int ni = 0; ni < 4; ++ni) {
      const int col = wn * 64 + ni * 16 + (lane & 15);
      #pragma unroll
      for (int j = 0; j < 4; ++j)
        sm.c[(row + j) * 136 + col] = (_Float16)(acc[mi][ni][j] + bv[ni]);
    }
  }
  __syncthreads();
  #pragma unroll
  for (int i = 0; i < 8; ++i) {
    const int ch  = tid + i * 256;   // 0..2047
    const int row = ch >> 4;         // 0..127
    const int cc  = ch & 15;         // 16B col-chunk
    const half8 v = *reinterpret_cast<const half8*>(&sm.c[row * 136 + cc * 8]);
    *reinterpret_cast<half8*>(&out[(size_t)(r0 + row) * DM + c0 + cc * 8]) = v;
  }
}

// ---------------------------------------------------------------------------
// Sampler v5. Block = 512 threads = 8 queries, XCD-swizzled grid
// (n = blockIdx&7 == XCD -> batch slice is in THIS XCD's L2, now including
// the dirty lines the XCD-aligned GEMM just wrote).
// Prep (t<256): (q,m,sub-level) -> 4-lane shfl softmax -> tap table in LDS.
// Gather (R10): read all 8 tap descriptors upfront, then depth-2 software-
// pipelined value loads (8 VMEM in flight vs the old 2) -> latency off the
// critical path; consume with fma_mix. shfl_xor(4) partner merge.
// ---------------------------------------------------------------------------
__global__ __launch_bounds__(512) void sample_k(
    const _Float16* __restrict__ proj,    // (N*LQ, 256) f16
    const float* __restrict__ refp,       // (N, LQ, 4)
    const _Float16* __restrict__ value,   // (N, 3840, 256) f16, c = m*32+d
    float* __restrict__ out)              // (N, LQ, 256)
{
  __shared__ uint4 tap_s[8][136];   // [q][m*17 + tap], 17.4 KB

  const int d     = blockIdx.x;
  const int n     = d & 7;
  const int chunk = d >> 3;
  const int row0q = n * LQn + chunk * 8;
  const int t     = threadIdx.x;

  const int lens[4]   = {2048, 1024, 512, 256};
  const int starts[4] = {0, 2048, 3072, 3584};

  // ---- prep: softmax + tap table ----
  if (t < 256) {
    const int q   = t >> 5;
    const int m   = (t >> 2) & 7;
    const int sub = t & 3;              // == level l
    const int j0  = m * 16 + sub * 4;
    const size_t prow = (size_t)(row0q + q) * DM;

    const half4 offv = *reinterpret_cast<const half4*>(&proj[prow + j0]);
    const half4 lgv  = *reinterpret_cast<const half4*>(&proj[prow + 128 + j0]);
    float lg[4], off[4];
    #pragma unroll
    for (int i = 0; i < 4; ++i) { lg[i] = (float)lgv[i]; off[i] = (float)offv[i]; }

    float mx = fmaxf(fmaxf(lg[0], lg[1]), fmaxf(lg[2], lg[3]));
    mx = fmaxf(mx, __shfl_xor(mx, 1));
    mx = fmaxf(mx, __shfl_xor(mx, 2));
    float e[4], s = 0.f;
    #pragma unroll
    for (int i = 0; i < 4; ++i) { e[i] = __expf(lg[i] - mx); s += e[i]; }
    s += __shfl_xor(s, 1);
    s += __shfl_xor(s, 2);
    const float inv = 1.f / s;

    const int   T  = lens[sub];
    const int   st = starts[sub];
    const float fT = (float)T;
    const float rf = refp[(size_t)(row0q + q) * 4 + sub];
    #pragma unroll
    for (int i = 0; i < 4; ++i) {
      const float a  = e[i] * inv;
      const float ix = fmaf(rf, fT, off[i] - 0.5f);
      const float fl = floorf(ix);
      const float w1 = ix - fl;
      const int   i0 = (int)fl;
      const int   i1 = i0 + 1;
      const float wa = (i0 >= 0 && i0 < T) ? a * (1.f - w1) : 0.f;
      const float wb = (i1 >= 0 && i1 < T) ? a * w1 : 0.f;
      const int   r0b = (st + min(max(i0, 0), T - 1)) * 512;
      const int   r1b = (st + min(max(i1, 0), T - 1)) * 512;
      union { half2v h; unsigned u; } pw;
      pw.h.x = (_Float16)wa; pw.h.y = (_Float16)wb;
      uint4 ent; ent.x = pw.u; ent.y = (unsigned)r0b; ent.z = (unsigned)r1b; ent.w = 0u;
      tap_s[q][m * 17 + sub * 4 + i] = ent;
    }
  }
  __syncthreads();

  // ---- gather (batch-issued, depth-2 pipelined) ----
  const int q  = t >> 6;          // wave id = query
  const int l  = t & 63;
  const int m  = l >> 3;
  const int dg = l & 3;
  const int th = (l >> 2) & 1;    // tap-half
  const char* vb = reinterpret_cast<const char*>(value) +
                   (size_t)n * S_TOT * 512 + m * 64 + dg * 16;

  uint4 e[8];
  #pragma unroll
  for (int i = 0; i < 8; ++i) e[i] = tap_s[q][m * 17 + th * 8 + i];

  float acc[8] = {};
  half8 v0[4], v1[4];
  #pragma unroll
  for (int i = 0; i < 4; ++i) {
    v0[i] = *reinterpret_cast<const half8*>(vb + e[i].y);
    v1[i] = *reinterpret_cast<const half8*>(vb + e[i].z);
  }
  #pragma unroll
  for (int i = 0; i < 8; ++i) {
    const int s = i & 3;
    union { unsigned u; half2v h; } pw; pw.u = e[i].x;
    const float wa = (float)pw.h.x;
    const float wb = (float)pw.h.y;
    const half8 a0 = v0[s];
    const half8 a1 = v1[s];
    if (i < 4) {   // prefetch second half while consuming first
      v0[s] = *reinterpret_cast<const half8*>(vb + e[i + 4].y);
      v1[s] = *reinterpret_cast<const half8*>(vb + e[i + 4].z);
    }
    #pragma unroll
    for (int j = 0; j < 8; ++j)
      acc[j] = fmaf(wa, (float)a0[j], fmaf(wb, (float)a1[j], acc[j]));
  }

  #pragma unroll
  for (int j = 0; j < 8; ++j) acc[j] += __shfl_xor(acc[j], 4);

  if (th == 0) {
    float* op = &out[(size_t)(row0q + q) * DM + m * 32 + dg * 8];
    f32x4 o0 = {acc[0], acc[1], acc[2], acc[3]};
    f32x4 o1 = {acc[4], acc[5], acc[6], acc[7]};
    *reinterpret_cast<f32x4*>(op)     = o0;
    *reinterpret_cast<f32x4*>(op + 4) = o1;
  }
}

}  // namespace

extern "C" void kernel_launch(void* const* d_in, const int* in_sizes, int n_in,
                              void* d_out, int out_size, void* d_ws, size_t ws_size,
                              hipStream_t stream) {
  const float* query  = (const float*)d_in[0];   // (8,2048,256)
  const float* refp   = (const float*)d_in[1];   // (8,2048,4,1)
  const float* inflat = (const float*)d_in[2];   // (8,3840,256)
  const float* W_val  = (const float*)d_in[5];   // (256,256)
  const float* b_val  = (const float*)d_in[6];   // (256,)
  const float* W_off  = (const float*)d_in[7];   // (128,256)
  const float* b_off  = (const float*)d_in[8];   // (128,)
  const float* W_attn = (const float*)d_in[9];   // (128,256)
  const float* b_attn = (const float*)d_in[10];  // (128,)
  float* out = (float*)d_out;

  // workspace: value f16 (30720*256 = 15.73 MB) | proj f16 (16384*256 = 8.4 MB)
  _Float16* value_h = (_Float16*)d_ws;
  _Float16* proj_h  = (_Float16*)((char*)d_ws +
                      (size_t)NB * S_TOT * DM * sizeof(_Float16));

  // merged GEMM: 480 value blocks + 256 proj blocks (XCD-aligned mapping)
  gemm_bf16_k<<<dim3(736), dim3(256), 0, stream>>>(
      inflat, query, W_val, b_val, W_off, b_off, W_attn, b_attn,
      value_h, proj_h);

  // softmax + bilinear sampling + head-mix (XCD-aligned to the GEMM's L2)
  sample_k<<<dim3(NB * LQn / 8), dim3(512), 0, stream>>>(
      proj_h, refp, value_h, out);
}